// Round 1
// 187.185 us; speedup vs baseline: 1.0018x; 1.0018x over previous
//
#include <hip/hip_runtime.h>

// SecureOptimizedBlockReLU (16,128,114,114) fp32 — register-resident, barrier-free.
// ch 0-31 passthrough copy; ch 32-79 2x2 block sign; ch 80-127 4x4 (28th block
// row/col are 2-wide at the 114 edge). sign = f32_block_sum > -1.0f, summed in
// the exact row-major sequential order verified bit-exact in R1-R6 (absmax 0.0).
//
// Evidence trail: strip-LDS kernel (R6, 65 us dispatch) showed VALUBusy 11.9%,
// HBM 31%, occupancy 71% -> latency/barrier-bound, not BW-bound. Each wg was
// serialized through two full-drain barriers around HBM load latency, and the
// store phase burned VALU on per-float4 div/mod. This version: every block sum
// fits in one lane's registers (2x2: two float2 rows; 4x4: eight float2s),
// so LDS and both barriers are eliminated entirely. Contiguous per-wave
// load/store segments (456 B per row across lanes) keep coalescing.
// NOTE: rows within a plane are 456 B apart (8 mod 16) -> odd rows are only
// 8B-aligned, hence float2 (not float4) accesses for classes B/C.

typedef float v4 __attribute__((ext_vector_type(4)));

#define PLANE  12996   // 114*114 floats
#define NBLK_A 6498    // 16*32*3249 float4 / 256 (exact) — ch 0..31 copy
#define NU_B   43776   // 768 planes * 57 row-pairs      — ch 32..79 (2x2)
#define NBLK_B 10944   // NU_B / 4 waves per block
#define NU_C   22272   // 768 planes * 29 block-rows     — ch 80..127 (4x4)
#define NBLK_C 5568    // NU_C / 4 waves per block

__global__ __launch_bounds__(256) void sbrelu_reg(const float* __restrict__ in,
                                                  float* __restrict__ out) {
    const int bid = blockIdx.x;
    const int tid = threadIdx.x;

    if (bid < NBLK_A) {
        // ---- class A: ch 0..31 pure float4 copy ----
        int idx = bid * 256 + tid;
        int n = idx / 103968;                 // 32*3249 float4 per n
        int off = n * 415872 + (idx - n * 103968);
        ((v4*)out)[off] = ((const v4*)in)[off];
        return;
    }

    const int lane = tid & 63;
    const int wid  = tid >> 6;

    if (bid < NBLK_A + NBLK_B) {
        // ---- class B: 2x2 blocks. One wave per (plane, row-pair). ----
        int u  = (bid - NBLK_A) * 4 + wid;     // [0, NU_B)
        int p  = u / 57;                       // plane 0..767
        int rp = u - 57 * p;                   // row-pair 0..56 (rows 2rp, 2rp+1)
        int n  = p / 48;
        int c  = 32 + (p - 48 * n);
        size_t base = (size_t)(n * 128 + c) * PLANE + 228 * rp;
        if (lane < 57) {
            const float2* i0 = (const float2*)(in + base) + lane;   // col 2*lane
            float2 a = i0[0];                  // row 2rp
            float2 b = i0[57];                 // row 2rp+1 (+456 B)
            float s = ((a.x + a.y) + b.x) + b.y;   // exact R1-R6 order
            float m = (s > -1.0f) ? 1.0f : 0.0f;
            float2* o0 = (float2*)(out + base) + lane;
            o0[0]  = make_float2(a.x * m, a.y * m);
            o0[57] = make_float2(b.x * m, b.y * m);
        }
        return;
    }

    // ---- class C: 4x4 blocks. One wave per (plane, block-row). ----
    int u  = (bid - NBLK_A - NBLK_B) * 4 + wid;  // [0, NU_C)
    int p  = u / 29;                             // plane 0..767
    int br = u - 29 * p;                         // block-row 0..28
    int n  = p / 48;
    int c  = 80 + (p - 48 * n);
    size_t base = (size_t)(n * 128 + c) * PLANE + 456 * br;
    if (lane >= 29) return;
    const bool full = (lane != 28);              // block-col 28 is 2 cols wide
    const float2* q  = (const float2*)(in  + base) + 2 * lane;   // col 4*lane
    float2*       qo = (float2*)      (out + base) + 2 * lane;

    if (br != 28) {
        // nh = 4 (rows 4br .. 4br+3); row stride = 57 float2
        float2 a0 = q[0],  a1 = q[57],  a2 = q[114], a3 = q[171];
        float2 b0 = make_float2(0.f, 0.f), b1 = b0, b2 = b0, b3 = b0;
        if (full) { b0 = q[1]; b1 = q[58]; b2 = q[115]; b3 = q[172]; }
        // exact row-major sequential sum (cols 4i,4i+1,4i+2,4i+3 per row)
        float s = 0.0f;
        s += a0.x; s += a0.y; if (full) { s += b0.x; s += b0.y; }
        s += a1.x; s += a1.y; if (full) { s += b1.x; s += b1.y; }
        s += a2.x; s += a2.y; if (full) { s += b2.x; s += b2.y; }
        s += a3.x; s += a3.y; if (full) { s += b3.x; s += b3.y; }
        float m = (s > -1.0f) ? 1.0f : 0.0f;
        qo[0]   = make_float2(a0.x * m, a0.y * m);
        qo[57]  = make_float2(a1.x * m, a1.y * m);
        qo[114] = make_float2(a2.x * m, a2.y * m);
        qo[171] = make_float2(a3.x * m, a3.y * m);
        if (full) {
            qo[1]   = make_float2(b0.x * m, b0.y * m);
            qo[58]  = make_float2(b1.x * m, b1.y * m);
            qo[115] = make_float2(b2.x * m, b2.y * m);
            qo[172] = make_float2(b3.x * m, b3.y * m);
        }
    } else {
        // global block-row 28: rows 112..113 only (nh = 2)
        float2 a0 = q[0], a1 = q[57];
        float2 b0 = make_float2(0.f, 0.f), b1 = b0;
        if (full) { b0 = q[1]; b1 = q[58]; }
        float s = 0.0f;
        s += a0.x; s += a0.y; if (full) { s += b0.x; s += b0.y; }
        s += a1.x; s += a1.y; if (full) { s += b1.x; s += b1.y; }
        float m = (s > -1.0f) ? 1.0f : 0.0f;
        qo[0]  = make_float2(a0.x * m, a0.y * m);
        qo[57] = make_float2(a1.x * m, a1.y * m);
        if (full) {
            qo[1]  = make_float2(b0.x * m, b0.y * m);
            qo[58] = make_float2(b1.x * m, b1.y * m);
        }
    }
}

extern "C" void kernel_launch(void* const* d_in, const int* in_sizes, int n_in,
                              void* d_out, int out_size, void* d_ws, size_t ws_size,
                              hipStream_t stream) {
    const float* in = (const float*)d_in[0];
    float* out = (float*)d_out;
    sbrelu_reg<<<NBLK_A + NBLK_B + NBLK_C, 256, 0, stream>>>(in, out);
}